// Round 1
// baseline (137.898 us; speedup 1.0000x reference)
//
#include <hip/hip_runtime.h>
#include <hip/hip_fp16.h>

// Triangulated-bilinear interp, B=8, N=262144 (512x512), T=2M targets.
// Round-6: keep interp_rec_kernel verbatim (verified 48.5us). Rewrite
// build_records: old version was ~40us (inferred: dur 136.7 = fill 48.5 +
// build + interp 48.5), issue-bound on 32 scalar 4B loads/thread.
// New builder: 2 cells/thread, float4 row loads (16 dwordx4/thread),
// batch-pair transpose via v_cvt_pkrtz (__float22half2_rn), 128B
// contiguous stores. Record layout byte-identical to previous rounds.

typedef float  f32x4 __attribute__((ext_vector_type(4)));
typedef unsigned int u32x4 __attribute__((ext_vector_type(4)));

union HalfPack8 { __half h[8]; u32x4 u; };

__device__ __forceinline__ unsigned pack_h2(float lo, float hi) {
    union { __half2 h2; unsigned u; } cv;
    cv.h2 = __float22half2_rn(make_float2(lo, hi));
    return cv.u;
}

// Fast record builder: thread owns cells (i0, j) and (i0+1, j).
// Per batch-pair q: 4x float4 loads (rows j, j+1 of batches 2q, 2q+1),
// pack halves (b2q, b2q+1) into u32 per corner. 16 loads / 8 stores thread.
__global__ __launch_bounds__(256) void build_records_fast(
    const float* __restrict__ x,   // (B=8, N)
    u32x4* __restrict__ rec,       // (ncells, 4) 16B chunks = 64B per cell
    const int* __restrict__ nx_p,
    int N)
{
    const int nx    = *nx_p;
    const int ny    = N / nx;
    const int ncx   = nx - 1;
    const int nrows = ny - 1;
    const int cpr   = (ncx + 1) >> 1;           // 2-cell chunks per row
    const int tid   = blockIdx.x * blockDim.x + threadIdx.x;
    if (tid >= cpr * nrows) return;
    const int j  = tid / cpr;
    const int i0 = (tid - j * cpr) * 2;
    const bool have2 = (i0 + 1 < ncx);

    unsigned c0[4][4];   // [chunk p00,p10,p01,p11][u32 q]  cell i0
    unsigned c1[4][4];   //                                 cell i0+1

    if (nx >= 4 && !(nx & 1)) {
        // Vector path (even nx>=4; i0 even => 8B-aligned dwordx4 loads).
        // Row end: shift the aligned window left by 2 and select (off2).
        const int  ld   = (i0 > nx - 4) ? (nx - 4) : i0;
        const bool off2 = (ld != i0);           // only last chunk of a row
        const long base = (long)j * nx + ld;
        #pragma unroll
        for (int q = 0; q < 4; ++q) {
            const float* pl = x + (long)(2 * q) * N + base;  // batch 2q
            const float* ph = pl + (long)N;                  // batch 2q+1
            f32x4 Al = *reinterpret_cast<const f32x4*>(pl);
            f32x4 Bl = *reinterpret_cast<const f32x4*>(pl + nx);
            f32x4 Ah = *reinterpret_cast<const f32x4*>(ph);
            f32x4 Bh = *reinterpret_cast<const f32x4*>(ph + nx);
            // positions i0, i0+1, i0+2 within the loaded window
            float a0l = off2 ? Al[2] : Al[0], a1l = off2 ? Al[3] : Al[1], a2l = Al[2];
            float b0l = off2 ? Bl[2] : Bl[0], b1l = off2 ? Bl[3] : Bl[1], b2l = Bl[2];
            float a0h = off2 ? Ah[2] : Ah[0], a1h = off2 ? Ah[3] : Ah[1], a2h = Ah[2];
            float b0h = off2 ? Bh[2] : Bh[0], b1h = off2 ? Bh[3] : Bh[1], b2h = Bh[2];
            c0[0][q] = pack_h2(a0l, a0h);   // p00
            c0[1][q] = pack_h2(a1l, a1h);   // p10
            c0[2][q] = pack_h2(b0l, b0h);   // p01
            c0[3][q] = pack_h2(b1l, b1h);   // p11
            c1[0][q] = pack_h2(a1l, a1h);
            c1[1][q] = pack_h2(a2l, a2h);
            c1[2][q] = pack_h2(b1l, b1h);
            c1[3][q] = pack_h2(b2l, b2h);
        }
    } else {
        // Safety net for tiny/odd nx: scalar corner loads.
        const long b00 = (long)j * nx + i0;
        #pragma unroll
        for (int q = 0; q < 4; ++q) {
            const float* pl = x + (long)(2 * q) * N;
            const float* ph = pl + (long)N;
            c0[0][q] = pack_h2(pl[b00],          ph[b00]);
            c0[1][q] = pack_h2(pl[b00 + 1],      ph[b00 + 1]);
            c0[2][q] = pack_h2(pl[b00 + nx],     ph[b00 + nx]);
            c0[3][q] = pack_h2(pl[b00 + nx + 1], ph[b00 + nx + 1]);
            if (have2) {
                c1[0][q] = pack_h2(pl[b00 + 1],          ph[b00 + 1]);
                c1[1][q] = pack_h2(pl[b00 + 2],          ph[b00 + 2]);
                c1[2][q] = pack_h2(pl[b00 + nx + 1],     ph[b00 + nx + 1]);
                c1[3][q] = pack_h2(pl[b00 + nx + 2],     ph[b00 + nx + 2]);
            } else {
                c1[0][q] = c1[1][q] = c1[2][q] = c1[3][q] = 0u;
            }
        }
    }

    u32x4* dst = rec + ((long)j * ncx + i0) * 4;
    #pragma unroll
    for (int ch = 0; ch < 4; ++ch)
        dst[ch] = (u32x4){ c0[ch][0], c0[ch][1], c0[ch][2], c0[ch][3] };
    if (have2) {
        #pragma unroll
        for (int ch = 0; ch < 4; ++ch)
            dst[4 + ch] = (u32x4){ c1[ch][0], c1[ch][1], c1[ch][2], c1[ch][3] };
    }
}

__device__ __forceinline__ void half8_to_float8(u32x4 u, float* f) {
    union { u32x4 v; __half2 h2[4]; } cv;
    cv.v = u;
    float2 a = __half22float2(cv.h2[0]); f[0] = a.x; f[1] = a.y;
    float2 b = __half22float2(cv.h2[1]); f[2] = b.x; f[3] = b.y;
    float2 c = __half22float2(cv.h2[2]); f[4] = c.x; f[5] = c.y;
    float2 d = __half22float2(cv.h2[3]); f[6] = d.x; f[7] = d.y;
}

__global__ __launch_bounds__(256, 2) void interp_rec_kernel(
    const u32x4* __restrict__ rec,   // (ncells, 4)
    const float* __restrict__ src_x,
    const float* __restrict__ src_y,
    const float* __restrict__ tgt_x,
    const float* __restrict__ tgt_y,
    const int* __restrict__ nx_p,
    float* __restrict__ out,
    int T, int N)
{
    const int nx = *nx_p;
    const int ny = N / nx;
    const int ncx = nx - 1;
    const float x0 = src_x[0];
    const float x1 = src_x[nx - 1];
    const float y0 = src_y[0];
    const float y1 = src_y[N - 1];
    const float dx = (x1 - x0) / (float)(nx - 1);
    const float dy = (y1 - y0) / (float)(ny - 1);

    const int t0 = (blockIdx.x * blockDim.x + threadIdx.x) * 4;
    if (t0 >= T) return;

    if (t0 + 4 <= T) {
        // Streaming reads: keep them out of L2 (rec wants the capacity).
        f32x4 tx4 = __builtin_nontemporal_load(
            reinterpret_cast<const f32x4*>(tgt_x + t0));
        f32x4 ty4 = __builtin_nontemporal_load(
            reinterpret_cast<const f32x4*>(tgt_y + t0));

        // ---- Phase 1: all addresses + weights (no memory waits) ----
        const u32x4* p0[4];
        const u32x4* p1[4];
        const u32x4* p2[4];
        float w0a[4], w1a[4], w2a[4];
        #pragma unroll
        for (int k = 0; k < 4; ++k) {
            float fx = (tx4[k] - x0) / dx;
            float fy = (ty4[k] - y0) / dy;
            float ix = fminf(fmaxf(floorf(fx), 0.0f), (float)(nx - 2));
            float iy = fminf(fmaxf(floorf(fy), 0.0f), (float)(ny - 2));
            float u = fx - ix;
            float v = fy - iy;
            bool lower = (u + v) <= 1.0f;
            int c = (int)iy * ncx + (int)ix;
            const u32x4* r = rec + (long)c * 4;
            p0[k] = r + (lower ? 0 : 3);
            p1[k] = r + 1;
            p2[k] = r + 2;
            w0a[k] = lower ? (1.0f - u - v) : (u + v - 1.0f);
            w1a[k] = lower ? u : (1.0f - v);
            w2a[k] = lower ? v : (1.0f - u);
        }

        // ---- Phase 2: issue ALL 12 loads before any use ----
        u32x4 r0[4], r1[4], r2[4];
        #pragma unroll
        for (int k = 0; k < 4; ++k) { r0[k] = *p0[k]; }
        #pragma unroll
        for (int k = 0; k < 4; ++k) { r1[k] = *p1[k]; }
        #pragma unroll
        for (int k = 0; k < 4; ++k) { r2[k] = *p2[k]; }

        // ---- Phase 3: convert + FMA ----
        float res[4][8];
        #pragma unroll
        for (int k = 0; k < 4; ++k) {
            float f0[8], f1[8], f2[8];
            half8_to_float8(r0[k], f0);
            half8_to_float8(r1[k], f1);
            half8_to_float8(r2[k], f2);
            #pragma unroll
            for (int b = 0; b < 8; ++b)
                res[k][b] = f0[b] * w0a[k] + f1[b] * w1a[k] + f2[b] * w2a[k];
        }

        // ---- Phase 4: non-temporal coalesced stores ----
        #pragma unroll
        for (int b = 0; b < 8; ++b) {
            f32x4 r4 = { res[0][b], res[1][b], res[2][b], res[3][b] };
            __builtin_nontemporal_store(
                r4, reinterpret_cast<f32x4*>(out + (long)b * T + t0));
        }
    } else {
        for (int t = t0; t < T; ++t) {
            float fx = (tgt_x[t] - x0) / dx;
            float fy = (tgt_y[t] - y0) / dy;
            float ix = fminf(fmaxf(floorf(fx), 0.0f), (float)(nx - 2));
            float iy = fminf(fmaxf(floorf(fy), 0.0f), (float)(ny - 2));
            float u = fx - ix;
            float v = fy - iy;
            bool lower = (u + v) <= 1.0f;
            int c = (int)iy * ncx + (int)ix;
            const u32x4* r = rec + (long)c * 4;
            u32x4 q0 = r[lower ? 0 : 3], q1 = r[1], q2 = r[2];
            float w0 = lower ? (1.0f - u - v) : (u + v - 1.0f);
            float w1 = lower ? u : (1.0f - v);
            float w2 = lower ? v : (1.0f - u);
            float f0[8], f1[8], f2[8];
            half8_to_float8(q0, f0);
            half8_to_float8(q1, f1);
            half8_to_float8(q2, f2);
            for (int b = 0; b < 8; ++b)
                out[(long)b * T + t] = f0[b] * w0 + f1[b] * w1 + f2[b] * w2;
        }
    }
}

// Fallback: direct fp32 path, used only if ws too small.
__global__ __launch_bounds__(256) void interp_fallback_kernel(
    const float* __restrict__ x,
    const float* __restrict__ src_x,
    const float* __restrict__ src_y,
    const float* __restrict__ tgt_x,
    const float* __restrict__ tgt_y,
    const int* __restrict__ nx_p,
    float* __restrict__ out,
    int T, int N, int B)
{
    const int nx = *nx_p;
    const int ny = N / nx;
    const float x0 = src_x[0];
    const float x1 = src_x[nx - 1];
    const float y0 = src_y[0];
    const float y1 = src_y[N - 1];
    const float dx = (x1 - x0) / (float)(nx - 1);
    const float dy = (y1 - y0) / (float)(ny - 1);

    const int t = blockIdx.x * blockDim.x + threadIdx.x;
    if (t >= T) return;
    float fx = (tgt_x[t] - x0) / dx;
    float fy = (tgt_y[t] - y0) / dy;
    float ix = fminf(fmaxf(floorf(fx), 0.0f), (float)(nx - 2));
    float iy = fminf(fmaxf(floorf(fy), 0.0f), (float)(ny - 2));
    float u = fx - ix;
    float v = fy - iy;
    int base = (int)iy * nx + (int)ix;
    bool lower = (u + v) <= 1.0f;
    int   i0 = lower ? base : (base + nx + 1);
    int   i1 = base + 1;
    int   i2 = base + nx;
    float w0 = lower ? (1.0f - u - v) : (u + v - 1.0f);
    float w1 = lower ? u : (1.0f - v);
    float w2 = lower ? v : (1.0f - u);
    for (int b = 0; b < B; ++b) {
        const float* xb = x + (long)b * N;
        out[(long)b * T + t] = xb[i0] * w0 + xb[i1] * w1 + xb[i2] * w2;
    }
}

extern "C" void kernel_launch(void* const* d_in, const int* in_sizes, int n_in,
                              void* d_out, int out_size, void* d_ws, size_t ws_size,
                              hipStream_t stream) {
    const float* x     = (const float*)d_in[0];
    const float* src_x = (const float*)d_in[1];
    const float* src_y = (const float*)d_in[2];
    const float* tgt_x = (const float*)d_in[3];
    const float* tgt_y = (const float*)d_in[4];
    const int*   nx_p  = (const int*)d_in[5];
    float* out = (float*)d_out;

    const int N = in_sizes[1];            // nx*ny = 262144
    const int T = in_sizes[3];            // 2,000,000
    const int B = in_sizes[0] / N;        // 8

    const size_t rec_bytes = (size_t)N * 64;

    if (B == 8 && ws_size >= rec_bytes) {
        u32x4* rec = (u32x4*)d_ws;
        {
            // 2 cells/thread; cpr*nrows <= N/2 always, in-kernel guard.
            const int block = 256;
            const int grid = (N / 2 + block - 1) / block;
            build_records_fast<<<grid, block, 0, stream>>>(x, rec, nx_p, N);
        }
        {
            const int threads_needed = (T + 3) / 4;
            const int block = 256;
            const int grid = (threads_needed + block - 1) / block;
            interp_rec_kernel<<<grid, block, 0, stream>>>(
                rec, src_x, src_y, tgt_x, tgt_y, nx_p, out, T, N);
        }
    } else {
        const int block = 256;
        const int grid = (T + block - 1) / block;
        interp_fallback_kernel<<<grid, block, 0, stream>>>(
            x, src_x, src_y, tgt_x, tgt_y, nx_p, out, T, N, B);
    }
}

// Round 2
// 129.366 us; speedup vs baseline: 1.0660x; 1.0660x over previous
//
#include <hip/hip_runtime.h>
#include <hip/hip_fp16.h>

// Triangulated-bilinear interp, B=8, N=262144 (512x512), T=2M targets.
// Round-7: L2-residency rewrite. The old 64B-per-CELL record (16.7MB)
// was 4x the per-XCD L2 (4MiB) -> ~75% L2 miss, latency-bound interp
// (VALUBusy 9%, FETCH 108MB). New layout: 16B per grid POINT (8 batches
// x fp16), total N*16B = exactly 4MiB -> L2-resident. Same 3 loads per
// target (g / g+1 / g+nx, triangle-selected corner), but ~200cy L2 hits
// instead of ~600-900cy L3/HBM. Builder becomes a pure coalesced pack
// (x read once: 8.4MB, write 4MiB). tgt/out stay nontemporal to keep
// L2 capacity for the grid.

typedef float  f32x4 __attribute__((ext_vector_type(4)));
typedef unsigned int u32x4 __attribute__((ext_vector_type(4)));

__device__ __forceinline__ unsigned pack_h2(float lo, float hi) {
    union { __half2 h2; unsigned u; } cv;
    cv.h2 = __float22half2_rn(make_float2(lo, hi));
    return cv.u;
}

// Grid pack: rec[p] = 16B = 8 halves {b0..b7} of x[b][p].
// 4 points/thread: 8x dwordx4 coalesced loads, 4x dwordx4 contiguous stores.
__global__ __launch_bounds__(256) void build_grid16(
    const float* __restrict__ x,   // (B=8, N)
    u32x4* __restrict__ rec,       // (N) 16B per grid point
    int N)
{
    const int p0 = (blockIdx.x * blockDim.x + threadIdx.x) * 4;
    if (p0 + 4 <= N) {
        f32x4 v[8];
        #pragma unroll
        for (int b = 0; b < 8; ++b)
            v[b] = *reinterpret_cast<const f32x4*>(x + (long)b * N + p0);
        #pragma unroll
        for (int k = 0; k < 4; ++k) {
            u32x4 r;
            r[0] = pack_h2(v[0][k], v[1][k]);
            r[1] = pack_h2(v[2][k], v[3][k]);
            r[2] = pack_h2(v[4][k], v[5][k]);
            r[3] = pack_h2(v[6][k], v[7][k]);
            rec[p0 + k] = r;
        }
    } else {
        for (int p = p0; p < N; ++p) {
            u32x4 r;
            r[0] = pack_h2(x[p], x[(long)N + p]);
            r[1] = pack_h2(x[2L * N + p], x[3L * N + p]);
            r[2] = pack_h2(x[4L * N + p], x[5L * N + p]);
            r[3] = pack_h2(x[6L * N + p], x[7L * N + p]);
            rec[p] = r;
        }
    }
}

__device__ __forceinline__ void half8_to_float8(u32x4 u, float* f) {
    union { u32x4 v; __half2 h2[4]; } cv;
    cv.v = u;
    float2 a = __half22float2(cv.h2[0]); f[0] = a.x; f[1] = a.y;
    float2 b = __half22float2(cv.h2[1]); f[2] = b.x; f[3] = b.y;
    float2 c = __half22float2(cv.h2[2]); f[4] = c.x; f[5] = c.y;
    float2 d = __half22float2(cv.h2[3]); f[6] = d.x; f[7] = d.y;
}

__global__ __launch_bounds__(256, 2) void interp_rec_kernel(
    const u32x4* __restrict__ rec,   // (N) 16B per grid point, L2-resident
    const float* __restrict__ src_x,
    const float* __restrict__ src_y,
    const float* __restrict__ tgt_x,
    const float* __restrict__ tgt_y,
    const int* __restrict__ nx_p,
    float* __restrict__ out,
    int T, int N)
{
    const int nx = *nx_p;
    const int ny = N / nx;
    const float x0 = src_x[0];
    const float x1 = src_x[nx - 1];
    const float y0 = src_y[0];
    const float y1 = src_y[N - 1];
    const float dx = (x1 - x0) / (float)(nx - 1);
    const float dy = (y1 - y0) / (float)(ny - 1);

    const int t0 = (blockIdx.x * blockDim.x + threadIdx.x) * 4;
    if (t0 >= T) return;

    if (t0 + 4 <= T) {
        // Streaming reads: keep them out of L2 (rec wants the capacity).
        f32x4 tx4 = __builtin_nontemporal_load(
            reinterpret_cast<const f32x4*>(tgt_x + t0));
        f32x4 ty4 = __builtin_nontemporal_load(
            reinterpret_cast<const f32x4*>(tgt_y + t0));

        // ---- Phase 1: all addresses + weights (no memory waits) ----
        const u32x4* p0[4];
        const u32x4* p1[4];
        const u32x4* p2[4];
        float w0a[4], w1a[4], w2a[4];
        #pragma unroll
        for (int k = 0; k < 4; ++k) {
            float fx = (tx4[k] - x0) / dx;
            float fy = (ty4[k] - y0) / dy;
            float ix = fminf(fmaxf(floorf(fx), 0.0f), (float)(nx - 2));
            float iy = fminf(fmaxf(floorf(fy), 0.0f), (float)(ny - 2));
            float u = fx - ix;
            float v = fy - iy;
            bool lower = (u + v) <= 1.0f;
            int g = (int)iy * nx + (int)ix;
            p0[k] = rec + g + (lower ? 0 : (nx + 1));  // p00 or p11
            p1[k] = rec + g + 1;                       // p10
            p2[k] = rec + g + nx;                      // p01
            w0a[k] = lower ? (1.0f - u - v) : (u + v - 1.0f);
            w1a[k] = lower ? u : (1.0f - v);
            w2a[k] = lower ? v : (1.0f - u);
        }

        // ---- Phase 2: issue ALL 12 loads before any use ----
        u32x4 r0[4], r1[4], r2[4];
        #pragma unroll
        for (int k = 0; k < 4; ++k) { r0[k] = *p0[k]; }
        #pragma unroll
        for (int k = 0; k < 4; ++k) { r1[k] = *p1[k]; }
        #pragma unroll
        for (int k = 0; k < 4; ++k) { r2[k] = *p2[k]; }

        // ---- Phase 3: convert + FMA ----
        float res[4][8];
        #pragma unroll
        for (int k = 0; k < 4; ++k) {
            float f0[8], f1[8], f2[8];
            half8_to_float8(r0[k], f0);
            half8_to_float8(r1[k], f1);
            half8_to_float8(r2[k], f2);
            #pragma unroll
            for (int b = 0; b < 8; ++b)
                res[k][b] = f0[b] * w0a[k] + f1[b] * w1a[k] + f2[b] * w2a[k];
        }

        // ---- Phase 4: non-temporal coalesced stores ----
        #pragma unroll
        for (int b = 0; b < 8; ++b) {
            f32x4 r4 = { res[0][b], res[1][b], res[2][b], res[3][b] };
            __builtin_nontemporal_store(
                r4, reinterpret_cast<f32x4*>(out + (long)b * T + t0));
        }
    } else {
        for (int t = t0; t < T; ++t) {
            float fx = (tgt_x[t] - x0) / dx;
            float fy = (tgt_y[t] - y0) / dy;
            float ix = fminf(fmaxf(floorf(fx), 0.0f), (float)(nx - 2));
            float iy = fminf(fmaxf(floorf(fy), 0.0f), (float)(ny - 2));
            float u = fx - ix;
            float v = fy - iy;
            bool lower = (u + v) <= 1.0f;
            int g = (int)iy * nx + (int)ix;
            u32x4 q0 = rec[g + (lower ? 0 : (nx + 1))];
            u32x4 q1 = rec[g + 1];
            u32x4 q2 = rec[g + nx];
            float w0 = lower ? (1.0f - u - v) : (u + v - 1.0f);
            float w1 = lower ? u : (1.0f - v);
            float w2 = lower ? v : (1.0f - u);
            float f0[8], f1[8], f2[8];
            half8_to_float8(q0, f0);
            half8_to_float8(q1, f1);
            half8_to_float8(q2, f2);
            for (int b = 0; b < 8; ++b)
                out[(long)b * T + t] = f0[b] * w0 + f1[b] * w1 + f2[b] * w2;
        }
    }
}

// Fallback: direct fp32 path, used only if ws too small / B != 8.
__global__ __launch_bounds__(256) void interp_fallback_kernel(
    const float* __restrict__ x,
    const float* __restrict__ src_x,
    const float* __restrict__ src_y,
    const float* __restrict__ tgt_x,
    const float* __restrict__ tgt_y,
    const int* __restrict__ nx_p,
    float* __restrict__ out,
    int T, int N, int B)
{
    const int nx = *nx_p;
    const int ny = N / nx;
    const float x0 = src_x[0];
    const float x1 = src_x[nx - 1];
    const float y0 = src_y[0];
    const float y1 = src_y[N - 1];
    const float dx = (x1 - x0) / (float)(nx - 1);
    const float dy = (y1 - y0) / (float)(ny - 1);

    const int t = blockIdx.x * blockDim.x + threadIdx.x;
    if (t >= T) return;
    float fx = (tgt_x[t] - x0) / dx;
    float fy = (tgt_y[t] - y0) / dy;
    float ix = fminf(fmaxf(floorf(fx), 0.0f), (float)(nx - 2));
    float iy = fminf(fmaxf(floorf(fy), 0.0f), (float)(ny - 2));
    float u = fx - ix;
    float v = fy - iy;
    int base = (int)iy * nx + (int)ix;
    bool lower = (u + v) <= 1.0f;
    int   i0 = lower ? base : (base + nx + 1);
    int   i1 = base + 1;
    int   i2 = base + nx;
    float w0 = lower ? (1.0f - u - v) : (u + v - 1.0f);
    float w1 = lower ? u : (1.0f - v);
    float w2 = lower ? v : (1.0f - u);
    for (int b = 0; b < B; ++b) {
        const float* xb = x + (long)b * N;
        out[(long)b * T + t] = xb[i0] * w0 + xb[i1] * w1 + xb[i2] * w2;
    }
}

extern "C" void kernel_launch(void* const* d_in, const int* in_sizes, int n_in,
                              void* d_out, int out_size, void* d_ws, size_t ws_size,
                              hipStream_t stream) {
    const float* x     = (const float*)d_in[0];
    const float* src_x = (const float*)d_in[1];
    const float* src_y = (const float*)d_in[2];
    const float* tgt_x = (const float*)d_in[3];
    const float* tgt_y = (const float*)d_in[4];
    const int*   nx_p  = (const int*)d_in[5];
    float* out = (float*)d_out;

    const int N = in_sizes[1];            // nx*ny = 262144
    const int T = in_sizes[3];            // 2,000,000
    const int B = in_sizes[0] / N;        // 8

    const size_t rec_bytes = (size_t)N * 16;   // 4 MiB at N=262144

    if (B == 8 && ws_size >= rec_bytes) {
        u32x4* rec = (u32x4*)d_ws;
        {
            const int block = 256;
            const int grid = ((N + 3) / 4 + block - 1) / block;
            build_grid16<<<grid, block, 0, stream>>>(x, rec, N);
        }
        {
            const int threads_needed = (T + 3) / 4;
            const int block = 256;
            const int grid = (threads_needed + block - 1) / block;
            interp_rec_kernel<<<grid, block, 0, stream>>>(
                rec, src_x, src_y, tgt_x, tgt_y, nx_p, out, T, N);
        }
    } else {
        const int block = 256;
        const int grid = (T + block - 1) / block;
        interp_fallback_kernel<<<grid, block, 0, stream>>>(
            x, src_x, src_y, tgt_x, tgt_y, nx_p, out, T, N, B);
    }
}